// Round 4
// baseline (204.703 us; speedup 1.0000x reference)
//
#include <hip/hip_runtime.h>
#include <hip/hip_fp16.h>

typedef _Float16 f16;
typedef _Float16 f16x8 __attribute__((ext_vector_type(8)));
typedef float f32x4 __attribute__((ext_vector_type(4)));

__device__ __forceinline__ f16x8 relu_add8(f16x8 a, f16x8 b) {
  f16x8 r;
#pragma unroll
  for (int i = 0; i < 8; i++) {
    f16 t = (f16)(a[i] + b[i]);
    r[i] = t > (f16)0 ? t : (f16)0;   // v_pk_add_f16 + v_pk_max_f16
  }
  return r;
}

// ---------------------------------------------------------------------------
// prep: pack both GEMM operands into MFMA-fragment order.
//  Btp: frag f = g*32+kb2 (g=j/16, kb2=k/32): lane l=q*16+cL holds
//       f16(x[g*16+cL] * W1[1][kb2*32+q*8+e]), e=0..7.  32*32 frags * 512 f16.
//  Wtp: frag f = cg*32+kb2: lane l holds f16(W2[kb2*32+q*8+e][cg*16+cL]).
// Each fragment is 1 KB contiguous -> K-loop loads are perfectly coalesced.
// ---------------------------------------------------------------------------
__global__ __launch_bounds__(256) void k_prep(const float* __restrict__ x,
                                              const float* __restrict__ W1,
                                              const float* __restrict__ W2,
                                              f16* __restrict__ Wtp,
                                              f16* __restrict__ Btp) {
  const int b = blockIdx.x, tid = threadIdx.x;
  if (b < 256) {                        // Btp: 65536 lane-slots
    const int t = b * 256 + tid;
    const int frag = t >> 6, l = t & 63;
    const int g = frag >> 5, kb2 = frag & 31;
    const int q = l >> 4, cL = l & 15;
    const int j = g * 16 + cL, k0 = kb2 * 32 + q * 8;
    const float xj = x[j];
    const float4 w0 = *(const float4*)(W1 + 1024 + k0);
    const float4 w1 = *(const float4*)(W1 + 1024 + k0 + 4);
    f16x8 o;
    o[0] = (f16)(xj * w0.x); o[1] = (f16)(xj * w0.y);
    o[2] = (f16)(xj * w0.z); o[3] = (f16)(xj * w0.w);
    o[4] = (f16)(xj * w1.x); o[5] = (f16)(xj * w1.y);
    o[6] = (f16)(xj * w1.z); o[7] = (f16)(xj * w1.w);
    *(f16x8*)(Btp + frag * 512 + l * 8) = o;
  } else if (b < 320) {                 // Wtp: 16384 lane-slots
    const int t = (b - 256) * 256 + tid;
    const int frag = t >> 6, l = t & 63;
    const int cg = frag >> 5, kb2 = frag & 31;
    const int q = l >> 4, cL = l & 15;
    const int n = cg * 16 + cL, k0 = kb2 * 32 + q * 8;
    f16x8 o;
#pragma unroll
    for (int e = 0; e < 8; e++) o[e] = (f16)W2[(k0 + e) * 128 + n];
    *(f16x8*)(Wtp + frag * 512 + l * 8) = o;
  }
}

// ---------------------------------------------------------------------------
// fused: block=(tj,i), 128 threads = 2 waves, each wave a 64x128 C-tile.
// K-loop: all operands register-resident (packed global loads), NO barriers,
// NO LDS traffic except 16B broadcast reads of ha.
// ---------------------------------------------------------------------------
__global__ __launch_bounds__(128) void k_fused(
    const float* __restrict__ x, const float* __restrict__ W1,
    const float* __restrict__ b1, const float* __restrict__ b2,
    const float* __restrict__ W3, const float* __restrict__ b3,
    const f16* __restrict__ Wtp, const f16* __restrict__ Btp,
    float* __restrict__ Kmat) {
  __shared__ f16 ha[1024];            // f16(x_i*W1[0][k] + b1[k])

  const int tid = threadIdx.x;
  const int i = blockIdx.y, tj = blockIdx.x;
  if (tj < (i >> 7)) return;          // tile entirely below diagonal
  const int j0 = tj << 7;

  {  // per-WG ha table
    const float xi = x[i];
    const int c8 = tid << 3;
    const float4 w0 = *(const float4*)(W1 + c8);
    const float4 w1 = *(const float4*)(W1 + c8 + 4);
    const float4 a0 = *(const float4*)(b1 + c8);
    const float4 a1 = *(const float4*)(b1 + c8 + 4);
    f16x8 o;
    o[0] = (f16)fmaf(xi, w0.x, a0.x); o[1] = (f16)fmaf(xi, w0.y, a0.y);
    o[2] = (f16)fmaf(xi, w0.z, a0.z); o[3] = (f16)fmaf(xi, w0.w, a0.w);
    o[4] = (f16)fmaf(xi, w1.x, a1.x); o[5] = (f16)fmaf(xi, w1.y, a1.y);
    o[6] = (f16)fmaf(xi, w1.z, a1.z); o[7] = (f16)fmaf(xi, w1.w, a1.w);
    *(f16x8*)(&ha[c8]) = o;
  }
  __syncthreads();

  const int lane = tid & 63, wv = tid >> 6;   // wave 0/1: rows wv*64..+63
  const int cL = lane & 15, q = lane >> 4;

  f32x4 acc[4][8];
  #pragma unroll
  for (int rg = 0; rg < 4; rg++)
    #pragma unroll
    for (int cg = 0; cg < 8; cg++) acc[rg][cg] = (f32x4){0.f, 0.f, 0.f, 0.f};

  // fragment base pointers (elements); +512 per kb2 step
  const f16* aptr[4];
  #pragma unroll
  for (int rg = 0; rg < 4; rg++) {
    const int g = (j0 >> 4) + wv * 4 + rg;
    aptr[rg] = Btp + g * (32 * 512) + lane * 8;
  }
  const f16* bptr[8];
  #pragma unroll
  for (int cg = 0; cg < 8; cg++)
    bptr[cg] = Wtp + cg * (32 * 512) + lane * 8;
  const f16* hptr = ha + q * 8;

  for (int kb2 = 0; kb2 < 32; ++kb2) {
    const f16x8 har = *(const f16x8*)(hptr);  hptr += 32;   // 16-lane broadcast
    f16x8 braw[8];
    #pragma unroll
    for (int cg = 0; cg < 8; cg++) { braw[cg] = *(const f16x8*)(bptr[cg]); bptr[cg] += 512; }
    f16x8 af[4];
    #pragma unroll
    for (int rg = 0; rg < 4; rg++) {
      const f16x8 araw = *(const f16x8*)(aptr[rg]); aptr[rg] += 512;
      af[rg] = relu_add8(araw, har);
    }
    #pragma unroll
    for (int cg = 0; cg < 8; cg++)
      #pragma unroll
      for (int rg = 0; rg < 4; rg++)
        acc[rg][cg] = __builtin_amdgcn_mfma_f32_16x16x32_f16(af[rg], braw[cg], acc[rg][cg], 0, 0, 0);
  }

  // --- epilogue: out[j] = dot(relu(acc + b2), w3) + b3, store if j >= i
  float b2v[8], w3v[8];
  #pragma unroll
  for (int cg = 0; cg < 8; cg++) {
    b2v[cg] = b2[cg * 16 + cL];
    w3v[cg] = W3[cg * 16 + cL];
  }
  const float b3s = b3[0];
  #pragma unroll
  for (int rg = 0; rg < 4; rg++) {
    #pragma unroll
    for (int r = 0; r < 4; r++) {
      float s = 0.f;
      #pragma unroll
      for (int cg = 0; cg < 8; cg++)
        s = fmaf(fmaxf(acc[rg][cg][r] + b2v[cg], 0.f), w3v[cg], s);
      s += __shfl_xor(s, 1, 64);
      s += __shfl_xor(s, 2, 64);
      s += __shfl_xor(s, 4, 64);
      s += __shfl_xor(s, 8, 64);
      if (cL == 0) {
        const int j = j0 + wv * 64 + rg * 16 + q * 4 + r;  // C row = quad*4+reg
        if (j >= i) Kmat[i * 512 + j] = s + b3s;
      }
    }
  }
}

// ---------------------------------------------------------------------------
// atta: C = K^T K, fp32. Below-diagonal K entries are UNWRITTEN -> masked to 0
// here (kills the memset). Symmetry (pb<=qb + mirror), i-loop stops at pb+32.
// ---------------------------------------------------------------------------
__global__ __launch_bounds__(256) void k_atta(const float* __restrict__ K,
                                              float* __restrict__ C) {
  const int pb = blockIdx.x * 32, qb = blockIdx.y * 32;
  if (pb > qb) return;
  __shared__ float sp[32][33], sq[32][33];
  const int tid = threadIdx.x;
  const int tx = tid & 15, ty = tid >> 4;
  float c00 = 0.f, c01 = 0.f, c10 = 0.f, c11 = 0.f;
  for (int i0 = 0; i0 < pb + 32; i0 += 32) {
    #pragma unroll
    for (int r = 0; r < 4; r++) {
      const int e = tid + 256 * r, ii = e >> 5, pp = e & 31;
      const int irow = i0 + ii;
      sp[ii][pp] = (irow <= pb + pp) ? K[irow * 512 + pb + pp] : 0.f;
      sq[ii][pp] = (irow <= qb + pp) ? K[irow * 512 + qb + pp] : 0.f;
    }
    __syncthreads();
    #pragma unroll 8
    for (int ii = 0; ii < 32; ii++) {
      const float a0 = sp[ii][ty * 2], a1 = sp[ii][ty * 2 + 1];
      const float b0 = sq[ii][tx * 2], b1 = sq[ii][tx * 2 + 1];
      c00 = fmaf(a0, b0, c00); c01 = fmaf(a0, b1, c01);
      c10 = fmaf(a1, b0, c10); c11 = fmaf(a1, b1, c11);
    }
    __syncthreads();
  }
  const int p0 = pb + ty * 2, q0 = qb + tx * 2;
  C[p0 * 512 + q0] = c00;       C[p0 * 512 + q0 + 1] = c01;
  C[(p0 + 1) * 512 + q0] = c10; C[(p0 + 1) * 512 + q0 + 1] = c11;
  C[q0 * 512 + p0] = c00;       C[(q0 + 1) * 512 + p0] = c01;
  C[q0 * 512 + p0 + 1] = c10;   C[(q0 + 1) * 512 + p0 + 1] = c11;
}

extern "C" void kernel_launch(void* const* d_in, const int* in_sizes, int n_in,
                              void* d_out, int out_size, void* d_ws, size_t ws_size,
                              hipStream_t stream) {
  const float* x  = (const float*)d_in[0];
  const float* W1 = (const float*)d_in[1];
  const float* b1 = (const float*)d_in[2];
  const float* W2 = (const float*)d_in[3];
  const float* b2 = (const float*)d_in[4];
  const float* W3 = (const float*)d_in[5];
  const float* b3 = (const float*)d_in[6];
  float* out = (float*)d_out;
  char* ws = (char*)d_ws;

  f16* Wtp    = (f16*)ws;                                   // 256 KB packed W2^T frags
  f16* Btp    = (f16*)(ws + (256 << 10));                   // 1 MB packed x_j*W1[1] frags
  float* Kmat = (float*)(ws + (256 << 10) + (1 << 20));     // 1 MB triu(out) (j>=i only)

  k_prep<<<320, 256, 0, stream>>>(x, W1, W2, Wtp, Btp);
  k_fused<<<dim3(4, 512), 128, 0, stream>>>(x, W1, b1, b2, W3, b3, Wtp, Btp, Kmat);
  k_atta<<<dim3(16, 16), 256, 0, stream>>>(Kmat, out);
}

// Round 5
// 173.703 us; speedup vs baseline: 1.1785x; 1.1785x over previous
//
#include <hip/hip_runtime.h>
#include <hip/hip_fp16.h>

typedef _Float16 f16;
typedef _Float16 f16x8 __attribute__((ext_vector_type(8)));
typedef float f32x4 __attribute__((ext_vector_type(4)));

__device__ __forceinline__ f16x8 relu8(f16x8 a) {
  f16x8 r;
#pragma unroll
  for (int i = 0; i < 8; i++) r[i] = a[i] > (f16)0 ? a[i] : (f16)0;
  return r;
}

// ---------------------------------------------------------------------------
// prep: Wtp[frag=cg*32+kb2][lane*8+e] = f16(W2[kb2*32+q*8+e][cg*16+cL])
// (B-fragment order for mfma_f32_16x16x32_f16; 1 KB contiguous per fragment)
// 256 frags * 64 lanes = 16384 slots -> 64 blocks.
// ---------------------------------------------------------------------------
__global__ __launch_bounds__(256) void k_prep(const float* __restrict__ W2,
                                              f16* __restrict__ Wtp) {
  const int t = blockIdx.x * 256 + threadIdx.x;
  const int frag = t >> 6, l = t & 63;
  const int cg = frag >> 5, kb2 = frag & 31;
  const int q = l >> 4, cL = l & 15;
  const int n = cg * 16 + cL, k0 = kb2 * 32 + q * 8;
  f16x8 o;
#pragma unroll
  for (int e = 0; e < 8; e++) o[e] = (f16)W2[(k0 + e) * 128 + n];
  *(f16x8*)(Wtp + frag * 512 + l * 8) = o;
}

// ---------------------------------------------------------------------------
// fused: block=(tj,i), 256 threads = 4 waves. Block tile: 256 j x 128 n.
// wave w: jh=w&1 (j-half of 128), nh=w>>1 (n-half of 64).
// A-fragments computed IN REGISTERS (relu(xj*w1v+hav), pk_fma/pk_max);
// only W2 fragments stream from global (4 x 1KB per iter, 1-deep prefetch).
// ---------------------------------------------------------------------------
__global__ __launch_bounds__(256, 2) void k_fused(
    const float* __restrict__ x, const float* __restrict__ W1,
    const float* __restrict__ b1, const float* __restrict__ b2,
    const float* __restrict__ W3, const float* __restrict__ b3,
    const f16* __restrict__ Wtp, float* __restrict__ Kmat) {
  __shared__ f16 ha[1024];    // f16(x_i*W1[0][k] + b1[k])
  __shared__ f16 w1b[1024];   // f16(W1[1][k])
  __shared__ float part[2][2][128];  // [nh][jh][j_local]

  const int tid = threadIdx.x;
  const int i = blockIdx.y, tj = blockIdx.x;
  if ((i >> 8) > tj) return;          // tile entirely below diagonal (uniform)
  const int j0 = tj << 8;

  {  // build ha + w1b tables (each half of the block does one)
    const float xi = x[i];
    if (tid < 128) {
      const int c8 = tid << 3;
      const float4 w0 = *(const float4*)(W1 + c8);
      const float4 w1 = *(const float4*)(W1 + c8 + 4);
      const float4 a0 = *(const float4*)(b1 + c8);
      const float4 a1 = *(const float4*)(b1 + c8 + 4);
      f16x8 o;
      o[0] = (f16)fmaf(xi, w0.x, a0.x); o[1] = (f16)fmaf(xi, w0.y, a0.y);
      o[2] = (f16)fmaf(xi, w0.z, a0.z); o[3] = (f16)fmaf(xi, w0.w, a0.w);
      o[4] = (f16)fmaf(xi, w1.x, a1.x); o[5] = (f16)fmaf(xi, w1.y, a1.y);
      o[6] = (f16)fmaf(xi, w1.z, a1.z); o[7] = (f16)fmaf(xi, w1.w, a1.w);
      *(f16x8*)(&ha[c8]) = o;
    } else {
      const int c8 = (tid - 128) << 3;
      const float4 w0 = *(const float4*)(W1 + 1024 + c8);
      const float4 w1 = *(const float4*)(W1 + 1024 + c8 + 4);
      f16x8 o;
      o[0] = (f16)w0.x; o[1] = (f16)w0.y; o[2] = (f16)w0.z; o[3] = (f16)w0.w;
      o[4] = (f16)w1.x; o[5] = (f16)w1.y; o[6] = (f16)w1.z; o[7] = (f16)w1.w;
      *(f16x8*)(&w1b[c8]) = o;
    }
  }
  __syncthreads();

  const int lane = tid & 63, wv = tid >> 6;
  const int jh = wv & 1, nh = wv >> 1;
  const int cL = lane & 15, q = lane >> 4;

  // per-lane x_j for the 8 j-groups this wave owns (A-frag m-index = cL)
  f16 xjs[8];
  #pragma unroll
  for (int rg = 0; rg < 8; rg++)
    xjs[rg] = (f16)x[j0 + jh * 128 + rg * 16 + cL];

  f32x4 acc[8][4];
  #pragma unroll
  for (int rg = 0; rg < 8; rg++)
    #pragma unroll
    for (int cg = 0; cg < 4; cg++) acc[rg][cg] = (f32x4){0.f, 0.f, 0.f, 0.f};

  // W2 fragment bases: cgGlob = nh*4+cg; frag = cgGlob*32 + kk
  const f16* wbase[4];
  #pragma unroll
  for (int cg = 0; cg < 4; cg++)
    wbase[cg] = Wtp + (nh * 4 + cg) * 16384 + lane * 8;

  const int phase = i & 31;           // per-block K-phase stagger
  int kk = phase;
  f16x8 cur[4], nxt[4];
  #pragma unroll
  for (int cg = 0; cg < 4; cg++) cur[cg] = *(const f16x8*)(wbase[cg] + (kk << 9));

  for (int t = 0; t < 32; ++t) {
    const int kn = (t + 1 + phase) & 31;
    // LDS broadcast reads (16B, 4 distinct addrs/wave)
    const f16x8 hav = *(const f16x8*)(&ha[kk * 32 + q * 8]);
    const f16x8 w1v = *(const f16x8*)(&w1b[kk * 32 + q * 8]);
    // prefetch next-iter W2 fragments (in flight during MFMAs)
    #pragma unroll
    for (int cg = 0; cg < 4; cg++) nxt[cg] = *(const f16x8*)(wbase[cg] + (kn << 9));
    // A-fragments in registers: relu(xj*w1v + hav)
    f16x8 af[8];
    #pragma unroll
    for (int rg = 0; rg < 8; rg++) {
      const f16 xs = xjs[rg];
      const f16x8 xv = {xs, xs, xs, xs, xs, xs, xs, xs};
      af[rg] = relu8(xv * w1v + hav);     // 4x v_pk_fma_f16 + 4x v_pk_max_f16
    }
    #pragma unroll
    for (int cg = 0; cg < 4; cg++)
      #pragma unroll
      for (int rg = 0; rg < 8; rg++)
        acc[rg][cg] = __builtin_amdgcn_mfma_f32_16x16x32_f16(af[rg], cur[cg], acc[rg][cg], 0, 0, 0);
    #pragma unroll
    for (int cg = 0; cg < 4; cg++) cur[cg] = nxt[cg];
    kk = kn;
  }

  // --- epilogue: partial dot over this wave's 64 n, then cross-nh LDS sum
  float b2v[4], w3v[4];
  #pragma unroll
  for (int cg = 0; cg < 4; cg++) {
    b2v[cg] = b2[nh * 64 + cg * 16 + cL];
    w3v[cg] = W3[nh * 64 + cg * 16 + cL];
  }
  #pragma unroll
  for (int rg = 0; rg < 8; rg++) {
    #pragma unroll
    for (int r = 0; r < 4; r++) {
      float s = 0.f;
      #pragma unroll
      for (int cg = 0; cg < 4; cg++)
        s = fmaf(fmaxf(acc[rg][cg][r] + b2v[cg], 0.f), w3v[cg], s);
      s += __shfl_xor(s, 1, 64);
      s += __shfl_xor(s, 2, 64);
      s += __shfl_xor(s, 4, 64);
      s += __shfl_xor(s, 8, 64);
      if (cL == 0) part[nh][jh][rg * 16 + q * 4 + r] = s;  // C row = q*4+reg
    }
  }
  __syncthreads();
  if (nh == 0) {
    const float b3s = b3[0];
    #pragma unroll
    for (int h = 0; h < 2; h++) {
      const int e = h * 64 + lane;
      const int j = j0 + jh * 128 + e;
      const float s = part[0][jh][e] + part[1][jh][e] + b3s;
      if (j >= i) Kmat[i * 512 + j] = s;
    }
  }
}

// ---------------------------------------------------------------------------
// atta: C = K^T K, fp32. Below-diagonal K entries UNWRITTEN -> masked to 0.
// Symmetry (pb<=qb + mirror), i-loop stops at pb+32.
// ---------------------------------------------------------------------------
__global__ __launch_bounds__(256) void k_atta(const float* __restrict__ K,
                                              float* __restrict__ C) {
  const int pb = blockIdx.x * 32, qb = blockIdx.y * 32;
  if (pb > qb) return;
  __shared__ float sp[32][33], sq[32][33];
  const int tid = threadIdx.x;
  const int tx = tid & 15, ty = tid >> 4;
  float c00 = 0.f, c01 = 0.f, c10 = 0.f, c11 = 0.f;
  for (int i0 = 0; i0 < pb + 32; i0 += 32) {
    #pragma unroll
    for (int r = 0; r < 4; r++) {
      const int e = tid + 256 * r, ii = e >> 5, pp = e & 31;
      const int irow = i0 + ii;
      sp[ii][pp] = (irow <= pb + pp) ? K[irow * 512 + pb + pp] : 0.f;
      sq[ii][pp] = (irow <= qb + pp) ? K[irow * 512 + qb + pp] : 0.f;
    }
    __syncthreads();
    #pragma unroll 8
    for (int ii = 0; ii < 32; ii++) {
      const float a0 = sp[ii][ty * 2], a1 = sp[ii][ty * 2 + 1];
      const float b0 = sq[ii][tx * 2], b1 = sq[ii][tx * 2 + 1];
      c00 = fmaf(a0, b0, c00); c01 = fmaf(a0, b1, c01);
      c10 = fmaf(a1, b0, c10); c11 = fmaf(a1, b1, c11);
    }
    __syncthreads();
  }
  const int p0 = pb + ty * 2, q0 = qb + tx * 2;
  C[p0 * 512 + q0] = c00;       C[p0 * 512 + q0 + 1] = c01;
  C[(p0 + 1) * 512 + q0] = c10; C[(p0 + 1) * 512 + q0 + 1] = c11;
  C[q0 * 512 + p0] = c00;       C[(q0 + 1) * 512 + p0] = c01;
  C[q0 * 512 + p0 + 1] = c10;   C[(q0 + 1) * 512 + p0 + 1] = c11;
}

extern "C" void kernel_launch(void* const* d_in, const int* in_sizes, int n_in,
                              void* d_out, int out_size, void* d_ws, size_t ws_size,
                              hipStream_t stream) {
  const float* x  = (const float*)d_in[0];
  const float* W1 = (const float*)d_in[1];
  const float* b1 = (const float*)d_in[2];
  const float* W2 = (const float*)d_in[3];
  const float* b2 = (const float*)d_in[4];
  const float* W3 = (const float*)d_in[5];
  const float* b3 = (const float*)d_in[6];
  float* out = (float*)d_out;
  char* ws = (char*)d_ws;

  f16* Wtp    = (f16*)ws;                          // 256 KB packed W2 B-fragments
  float* Kmat = (float*)(ws + (256 << 10));        // 1 MB triu(out) (j>=i written)

  k_prep<<<64, 256, 0, stream>>>(W2, Wtp);
  k_fused<<<dim3(2, 512), 256, 0, stream>>>(x, W1, b1, b2, W3, b3, Wtp, Kmat);
  k_atta<<<dim3(16, 16), 256, 0, stream>>>(Kmat, out);
}